// Round 5
// baseline (49.361 us; speedup 1.0000x reference)
//
#include <hip/hip_runtime.h>

typedef float f32x4 __attribute__((ext_vector_type(4)));

// Problem constants (from reference setup_inputs)
#define B_DIM   4
#define A_DIM   200
#define F_DIM   128
#define OUT_DIM 128
#define NROW    (B_DIM * A_DIM)          // 800
#define HJ_OFF  (NROW * (OUT_DIM / 4))   // f32x4 offset of h_j block
#define JRC     40                       // jrows per block (200 % 40 == 0)
#define JRW     10                       // jrows per wave (4 waves/block)

// Kernel A: per-(b,a)-row dual half-GEMM.
// h layout in workspace: [0 .. 800*128)         = h_i + bias
//                        [800*128 .. 2*800*128) = h_j
__global__ void __launch_bounds__(128) gemm_h_kernel(
    const float* __restrict__ x,      // [B*A, F]
    const float* __restrict__ W,      // [2F, OUT]
    const float* __restrict__ bias,   // [OUT]
    float* __restrict__ h)            // [2, B*A, OUT]
{
    const int row = blockIdx.x;       // 0..799  (b*A + a)
    const int o   = threadIdx.x;      // 0..127
    __shared__ float xs[F_DIM];
    xs[o] = x[row * F_DIM + o];
    __syncthreads();

    float acc1 = 0.f, acc2 = 0.f;
#pragma unroll
    for (int f = 0; f < F_DIM; ++f) {
        const float xv = xs[f];                       // LDS broadcast, no conflict
        acc1 = fmaf(xv, W[f * OUT_DIM + o], acc1);            // W[:F] coalesced
        acc2 = fmaf(xv, W[(F_DIM + f) * OUT_DIM + o], acc2);  // W[F:] coalesced
    }
    h[row * OUT_DIM + o]          = acc1 + bias[o];
    h[(NROW + row) * OUT_DIM + o] = acc2;
}

// Kernel B: write-bound broadcast expand, wave-private LDS staging, NO barrier.
// Block = 256 threads = 40 consecutive jrows (one birow; 200%40==0).
// Each wave owns 10 jrows: phase 1 fills its own LDS region (coalesced read
// burst), phase 2 is a pure 15-store/lane contiguous burst. No cross-wave
// dependency -> no __syncthreads; waves stream independently like memset.
__global__ void __launch_bounds__(256) expand_kernel(
    const f32x4* __restrict__ h4,     // hi4 then hj4
    const float* __restrict__ dist,   // [B*A*A*3]
    f32x4* __restrict__ out)          // [B*A*A*3*(OUT/4)]
{
    __shared__ f32x4 pairLDS[JRC * 32];   // 20 KB
    __shared__ float distLDS[JRC * 3];    // 480 B

    const unsigned t     = threadIdx.x;
    const unsigned l     = t & 63u;              // lane
    const unsigned wv    = t >> 6;               // wave 0..3
    const unsigned o4    = l & 31u;
    const unsigned jlh   = l >> 5;               // 0..1 (half-wave row offset)
    const unsigned jrow0 = blockIdx.x * JRC;

    const unsigned birow = jrow0 / 200u;         // same for all 40 jrows
    const unsigned j0    = jrow0 - birow * 200u;
    const unsigned b     = birow / 200u;

    // Phase 1: this wave's read burst -> its own LDS region (rows wv*10..+10)
    const f32x4 hi = h4[birow * 32u + o4];       // L1/L2-resident broadcast row
#pragma unroll
    for (int k = 0; k < 5; ++k) {
        const unsigned jl = wv * JRW + jlh + 2u * k;         // 10 rows / 2 halves
        const f32x4 hj = h4[HJ_OFF + (b * 200u + j0 + jl) * 32u + o4];
        pairLDS[jl * 32u + o4] = hi + hj;
    }
    if (l < JRW * 3u)                                        // 30 floats per wave
        distLDS[wv * (JRW * 3u) + l] = dist[(jrow0 + wv * JRW) * 3u + l];
    // no __syncthreads: each wave reads back only what it wrote (lgkmcnt orders)

    // Phase 2: pure store burst — 960 float4 per wave, 15 per lane, contiguous
    f32x4* __restrict__ obase = out + jrow0 * 96u + wv * 960u;
#pragma unroll
    for (int k = 0; k < 15; ++k) {
        const unsigned lidx = l + 64u * k;       // 0..959 within wave chunk
        const unsigned rl   = lidx >> 5;         // 0..29  (= jl_local*3 + c)
        const unsigned jll  = rl / 3u;           // magic-mul
        const f32x4 pv = pairLDS[(wv * JRW + jll) * 32u + (lidx & 31u)];
        const float  d  = distLDS[wv * (JRW * 3u) + rl];
        obase[lidx] = pv * d;
    }
}

extern "C" void kernel_launch(void* const* d_in, const int* in_sizes, int n_in,
                              void* d_out, int out_size, void* d_ws, size_t ws_size,
                              hipStream_t stream) {
    const float* x    = (const float*)d_in[0];   // scalar_features [B,A,F]
    const float* dist = (const float*)d_in[1];   // distances [B,A,A,3]
    const float* W    = (const float*)d_in[2];   // weight [2F,OUT]
    const float* bias = (const float*)d_in[3];   // bias [OUT]

    float* h = (float*)d_ws;  // needs 2*800*128*4 = 819,200 B of scratch

    gemm_h_kernel<<<NROW, F_DIM, 0, stream>>>(x, W, bias, h);

    // 160000 jrows / 40 per block = 4000 blocks of 256 threads
    expand_kernel<<<160000 / JRC, 256, 0, stream>>>((const f32x4*)h, dist,
                                                    (f32x4*)d_out);
}

// Round 6
// 48.811 us; speedup vs baseline: 1.0113x; 1.0113x over previous
//
#include <hip/hip_runtime.h>

typedef float f32x4 __attribute__((ext_vector_type(4)));

// Problem constants (from reference setup_inputs)
#define B_DIM   4
#define A_DIM   200
#define F_DIM   128
#define OUT_DIM 128
#define NROW    (B_DIM * A_DIM)          // 800
#define HJ_OFF  (NROW * (OUT_DIM / 4))   // f32x4 offset of h_j block
#define JRC     40                       // jrows per block (200 % 40 == 0)
#define JRW     10                       // jrows per wave (4 waves/block)

// Kernel A: per-(b,a)-row dual half-GEMM, 256 threads (half = W-half).
// h layout in workspace: [0 .. 800*128)         = h_i + bias
//                        [800*128 .. 2*800*128) = h_j
__global__ void __launch_bounds__(256) gemm_h_kernel(
    const float* __restrict__ x,      // [B*A, F]
    const float* __restrict__ W,      // [2F, OUT]
    const float* __restrict__ bias,   // [OUT]
    float* __restrict__ h)            // [2, B*A, OUT]
{
    const int row  = blockIdx.x;      // 0..799  (b*A + a)
    const int t    = threadIdx.x;
    const int o    = t & 127;         // 0..127
    const int half = t >> 7;          // 0: W[:F], 1: W[F:]
    __shared__ float xs[F_DIM];
    if (t < F_DIM) xs[t] = x[row * F_DIM + t];
    __syncthreads();

    const float* __restrict__ Wh = W + half * F_DIM * OUT_DIM;
    float acc = 0.f;
#pragma unroll
    for (int f = 0; f < F_DIM; ++f)
        acc = fmaf(xs[f], Wh[f * OUT_DIM + o], acc);   // coalesced, L2-hot

    if (half == 0) h[row * OUT_DIM + o]          = acc + bias[o];
    else           h[(NROW + row) * OUT_DIM + o] = acc;
}

// Kernel B: write-bound broadcast expand, fully register-resident.
// Block = 256 threads = 40 consecutive jrows (one birow; 200%40==0).
// Each wave owns 10 jrows. Lane l: o4 = l&31, jlh = l>>5 (even/odd row).
// Phase 1: 5 pair vectors + 15 dist scalars -> VGPRs (no LDS, no barrier).
// Phase 2: 15 back-to-back global_store_dwordx4, each lane storing the same
// column it loaded (wave-store = 2 x 512B contiguous segments).
__global__ void __launch_bounds__(256) expand_kernel(
    const f32x4* __restrict__ h4,     // hi4 then hj4
    const float* __restrict__ dist,   // [B*A*A*3]
    f32x4* __restrict__ out)          // [B*A*A*3*(OUT/4)]
{
    const unsigned t     = threadIdx.x;
    const unsigned l     = t & 63u;              // lane
    const unsigned wv    = t >> 6;               // wave 0..3
    const unsigned o4    = l & 31u;
    const unsigned jlh   = l >> 5;               // 0..1 (even/odd row of pair)
    const unsigned jrow0 = blockIdx.x * JRC;

    const unsigned birow = jrow0 / 200u;         // same for all 40 jrows
    const unsigned j0    = jrow0 - birow * 200u;
    const unsigned b     = birow / 200u;

    const unsigned wrow  = jrow0 + wv * JRW;     // first jrow of this wave
    const f32x4 hi = h4[birow * 32u + o4];       // L1/L2-resident broadcast row

    // Phase 1: reads -> registers. Lane owns rows {2k + jlh}, k=0..4.
    f32x4 p[5];
    float d[5][3];
#pragma unroll
    for (int k = 0; k < 5; ++k) {
        const unsigned r = 2u * k + jlh;                     // row within wave
        const f32x4 hj = h4[HJ_OFF + (b * 200u + j0 + wv * JRW + r) * 32u + o4];
        p[k] = hi + hj;
        d[k][0] = dist[(wrow + r) * 3u + 0u];
        d[k][1] = dist[(wrow + r) * 3u + 1u];
        d[k][2] = dist[(wrow + r) * 3u + 2u];
    }

    // Phase 2: pure store burst, all operands in VGPRs.
    f32x4* __restrict__ obase = out + (unsigned long long)wrow * 96ull;
#pragma unroll
    for (int k = 0; k < 5; ++k) {
        const unsigned rbase = (2u * k + jlh) * 96u + o4;
        obase[rbase +  0u] = p[k] * d[k][0];
        obase[rbase + 32u] = p[k] * d[k][1];
        obase[rbase + 64u] = p[k] * d[k][2];
    }
}

extern "C" void kernel_launch(void* const* d_in, const int* in_sizes, int n_in,
                              void* d_out, int out_size, void* d_ws, size_t ws_size,
                              hipStream_t stream) {
    const float* x    = (const float*)d_in[0];   // scalar_features [B,A,F]
    const float* dist = (const float*)d_in[1];   // distances [B,A,A,3]
    const float* W    = (const float*)d_in[2];   // weight [2F,OUT]
    const float* bias = (const float*)d_in[3];   // bias [OUT]

    float* h = (float*)d_ws;  // needs 2*800*128*4 = 819,200 B of scratch

    gemm_h_kernel<<<NROW, 256, 0, stream>>>(x, W, bias, h);

    // 160000 jrows / 40 per block = 4000 blocks of 256 threads
    expand_kernel<<<160000 / JRC, 256, 0, stream>>>((const f32x4*)h, dist,
                                                    (f32x4*)d_out);
}